// Round 3
// baseline (9316.019 us; speedup 1.0000x reference)
//
#include <hip/hip_runtime.h>
#include <hip/hip_bf16.h>
#include <stdint.h>

#define T_STEPS 16
#define NN      20000
#define EE      640000
#define FF      64
#define HH      128
#define CC      16
#define BN_EPS  1e-5f

typedef __hip_bfloat16 bf16;

// flag-aware float read: isbf ? bf16[i] : float[i]
__device__ __forceinline__ float rdf(const void* p, long i, int isbf){
  return isbf ? __bfloat162float(((const bf16*)p)[i]) : ((const float*)p)[i];
}

// ---------------- dtype probe ----------------
// Sample even uint16 halfwords of x_seq (~N(0,1)). If buffer is bf16, nearly all
// have exponent ~127; if fp32, even halfwords are low mantissa bits (~4% match).
__global__ void k_detect(const void* x, int* flag){
  __shared__ int sh[256];
  int tid = threadIdx.x;
  const uint16_t* u = (const uint16_t*)x;
  uint16_t v = u[2*tid];               // in-bounds under either dtype
  int e = (v >> 7) & 0xFF;
  sh[tid] = (e >= 120 && e <= 134) ? 1 : 0;
  __syncthreads();
  for (int o = 128; o; o >>= 1){ if (tid < o) sh[tid] += sh[tid+o]; __syncthreads(); }
  if (tid == 0) flag[0] = (sh[0] >= 128) ? 1 : 0;
}

// ---------------- setup kernels ----------------
__global__ void k_init(float* deg, int* cnt, int* cursor, int n){
  int i = blockIdx.x*blockDim.x + threadIdx.x;
  if (i < n){ deg[i] = 1.0f; cnt[i] = 0; cursor[i] = 0; }   // deg=1: self-loop weight
}

__global__ void k_deg(const int* src, const int* dst, const void* w,
                      float* deg, int* cnt, int e, const int* flag){
  int i = blockIdx.x*blockDim.x + threadIdx.x;
  if (i < e){
    int d = dst[i];
    atomicAdd(&deg[d], rdf(w, i, *flag));
    atomicAdd(&cnt[d], 1);
  }
}

__global__ void k_dinv(const float* deg, float* dinv, float* selfnorm, int n){
  int i = blockIdx.x*blockDim.x + threadIdx.x;
  if (i < n){
    float d = deg[i];
    float r = d > 0.f ? rsqrtf(d) : 0.f;
    dinv[i] = r; selfnorm[i] = r*r;
  }
}

// single-block exclusive scan of cnt[0..n) -> offs[0..n]
__global__ void k_scan(const int* cnt, int* offs, int n){
  __shared__ int part[256];
  int tid = threadIdx.x;
  int chunk = (n + 255)/256;
  int lo = tid*chunk; int hi = lo + chunk;
  if (hi > n) hi = n;
  if (lo > n) lo = n;
  int s = 0;
  for (int i = lo; i < hi; i++) s += cnt[i];
  part[tid] = s;
  __syncthreads();
  for (int off = 1; off < 256; off <<= 1){
    int t = (tid >= off) ? part[tid-off] : 0;
    __syncthreads();
    part[tid] += t;
    __syncthreads();
  }
  int run = part[tid] - s;          // exclusive prefix
  for (int i = lo; i < hi; i++){ offs[i] = run; run += cnt[i]; }
  if (tid == 255) offs[n] = part[255];
}

__global__ void k_fill(const int* src, const int* dst, const void* w, const float* dinv,
                       const int* offs, int* cursor, int* csr_src, float* csr_norm, int e,
                       const int* flag){
  int i = blockIdx.x*blockDim.x + threadIdx.x;
  if (i < e){
    int s = src[i], d = dst[i];
    int pos = offs[d] + atomicAdd(&cursor[d], 1);
    csr_src[pos]  = s;
    csr_norm[pos] = dinv[s] * rdf(w, i, *flag) * dinv[d];
  }
}

// flag-aware convert (with element offset into src)
__global__ void k_cvt(const void* src, long off, float* dst, int n, const int* flag){
  int i = blockIdx.x*blockDim.x + threadIdx.x;
  if (i < n) dst[i] = rdf(src, off + i, *flag);
}

// src [R,C] -> dst [C,R] fp32
__global__ void k_cvt_t(const void* src, float* dst, int R, int C, const int* flag){
  int i = blockIdx.x*blockDim.x + threadIdx.x;
  if (i < R*C){ int r = i / C, c = i % C; dst[c*R + r] = rdf(src, i, *flag); }
}

__global__ void k_zero(float* p, int n){
  int i = blockIdx.x*blockDim.x + threadIdx.x;
  if (i < n) p[i] = 0.f;
}

// ---------------- GEMM: C[M,N] = act(A[M,K] @ B[K,N] + bias) ----------------
// 64x64 tile, 16x16 threads x (4x4)/thread. N mult of 64, K mult of 16.
template<int RELU>
__global__ void k_gemm(const float* A, const float* B, const float* bias,
                       float* C, int M, int N, int K){
  __shared__ float As[16][65];   // [k][m]
  __shared__ float Bs[16][65];   // [k][n]
  int tx = threadIdx.x, ty = threadIdx.y;
  int tid = ty*16 + tx;
  int bm = blockIdx.y * 64;
  int bn = blockIdx.x * 64;
  float acc[4][4] = {};
  for (int k0 = 0; k0 < K; k0 += 16){
    int row = tid >> 2;
    int ks  = (tid & 3) << 2;
    int gr  = bm + row;
    if (gr < M){
      const float* pa = &A[(size_t)gr*K + k0 + ks];
      #pragma unroll
      for (int j = 0; j < 4; j++) As[ks+j][row] = pa[j];
    } else {
      #pragma unroll
      for (int j = 0; j < 4; j++) As[ks+j][row] = 0.f;
    }
    int kr = tid >> 4;
    int nc = (tid & 15) << 2;
    const float* pb = &B[(size_t)(k0+kr)*N + bn + nc];
    #pragma unroll
    for (int j = 0; j < 4; j++) Bs[kr][nc+j] = pb[j];
    __syncthreads();
    #pragma unroll
    for (int kk = 0; kk < 16; kk++){
      float a[4], b[4];
      #pragma unroll
      for (int i = 0; i < 4; i++) a[i] = As[kk][ty*4+i];
      #pragma unroll
      for (int j = 0; j < 4; j++) b[j] = Bs[kk][tx*4+j];
      #pragma unroll
      for (int i = 0; i < 4; i++)
        #pragma unroll
        for (int j = 0; j < 4; j++) acc[i][j] += a[i]*b[j];
    }
    __syncthreads();
  }
  #pragma unroll
  for (int i = 0; i < 4; i++){
    int gr = bm + ty*4 + i;
    if (gr >= M) break;
    #pragma unroll
    for (int j = 0; j < 4; j++){
      int gc = bn + tx*4 + j;
      float v = acc[i][j];
      if (bias) v += bias[gc];
      if (RELU) v = fmaxf(v, 0.f);
      C[(size_t)gr*N + gc] = v;
    }
  }
}

// ---------------- GCN conv (gather over CSR), one timestep ----------------
__global__ void k_conv(const float* in, float* out, const int* offs,
                       const int* csr_src, const float* csr_norm,
                       const float* selfnorm){
  int n = blockIdx.x, h = threadIdx.x;
  float acc = selfnorm[n] * in[(size_t)n*HH + h];
  int i0 = offs[n], i1 = offs[n+1];
  for (int i = i0; i < i1; i++)
    acc += csr_norm[i] * in[(size_t)csr_src[i]*HH + h];
  out[(size_t)n*HH + h] = acc;
}

// ---------------- BatchNorm stats (one timestep): sums[0:H]=sum, sums[H:2H]=sumsq
__global__ void k_bnstats(const float* x, float* sums){
  int h  = threadIdx.x & 127;
  int ry = threadIdx.x >> 7;
  int rowsPer = (NN + gridDim.x - 1) / gridDim.x;
  int r0 = blockIdx.x * rowsPer;
  int r1 = r0 + rowsPer; if (r1 > NN) r1 = NN;
  float s = 0.f, ss = 0.f;
  for (int r = r0 + ry; r < r1; r += 2){
    float v = x[(size_t)r*HH + h];
    s += v; ss += v*v;
  }
  __shared__ float sh[2][HH], shq[2][HH];
  sh[ry][h] = s; shq[ry][h] = ss;
  __syncthreads();
  if (ry == 0){
    atomicAdd(&sums[h],      sh[0][h] + sh[1][h]);
    atomicAdd(&sums[HH + h], shq[0][h] + shq[1][h]);
  }
}

__global__ void k_bnnorm(float* x, const float* sums,
                         const float* g, const float* be, int total){
  int idx = blockIdx.x*blockDim.x + threadIdx.x;
  if (idx >= total) return;
  int h = idx & (HH-1);
  float inv_n = 1.0f / (float)NN;
  float mu  = sums[h] * inv_n;
  float var = sums[HH + h] * inv_n - mu*mu;
  var = fmaxf(var, 0.f);
  float v = (x[idx] - mu) * rsqrtf(var + BN_EPS) * g[h] + be[h];
  x[idx] = fmaxf(v, 0.f);   // relu fused
}

// ---------------- GRU pointwise ----------------
__global__ void k_gru(const float* gi, const float* gh, float* h, int total){
  int idx = blockIdx.x*blockDim.x + threadIdx.x;
  if (idx >= total) return;
  int n = idx >> 7, k = idx & 127;
  const float* gin = gi + (size_t)n*(3*HH);
  const float* ghn = gh + (size_t)n*(3*HH);
  float ir = gin[k], iz = gin[k+HH], inn = gin[k+2*HH];
  float hr = ghn[k], hz = ghn[k+HH], hn  = ghn[k+2*HH];
  float r = 1.f/(1.f + expf(-(ir+hr)));
  float z = 1.f/(1.f + expf(-(iz+hz)));
  float nc = tanhf(inn + r*hn);
  float hp = h[idx];
  h[idx] = (1.f - z)*nc + z*hp;
}

// ---------------- output head: h@W_out + b_out, log_softmax ----------------
__global__ void k_out(const float* h, const float* Wo, const float* bo, void* out, int n,
                      const int* flag){
  __shared__ float Ws[HH][CC+1];
  __shared__ float bs[CC];
  int tid = threadIdx.x;
  for (int i = tid; i < HH*CC; i += 256) Ws[i/CC][i%CC] = Wo[i];
  if (tid < CC) bs[tid] = bo[tid];
  __syncthreads();
  int row = blockIdx.x*16 + (tid >> 4);
  int c   = tid & 15;
  if (row >= n) return;
  const float* hr = h + (size_t)row*HH;
  float s = bs[c];
  #pragma unroll 8
  for (int j = 0; j < HH; j++) s += hr[j]*Ws[j][c];
  float m = s;
  for (int o = 8; o; o >>= 1) m = fmaxf(m, __shfl_xor(m, o, 16));
  float e = expf(s - m);
  float sum = e;
  for (int o = 8; o; o >>= 1) sum += __shfl_xor(sum, o, 16);
  float v = s - m - logf(sum);
  size_t idx = (size_t)row*CC + c;
  if (*flag) ((bf16*)out)[idx] = __float2bfloat16(v);
  else       ((float*)out)[idx] = v;
}

// ---------------- launcher ----------------
static inline size_t alignup(size_t x){ return (x + 255) & ~(size_t)255; }
static inline int ceil_div(int a, int b){ return (a + b - 1)/b; }

extern "C" void kernel_launch(void* const* d_in, const int* in_sizes, int n_in,
                              void* d_out, int out_size, void* d_ws, size_t ws_size,
                              hipStream_t stream){
  const void* x_seq = d_in[0];
  const int*  eidx  = (const int*)d_in[1];
  const void* ew    = d_in[2];
  const void* W_in  = d_in[3];
  const void* b_in  = d_in[4];
  const void* W1    = d_in[5];
  // d_in[6] = bc1 : additive per-column const, cancels exactly under training-mode BN
  const void* g1    = d_in[7];
  const void* be1   = d_in[8];
  const void* W2    = d_in[9];
  // d_in[10] = bc2 : cancels under BN
  const void* g2    = d_in[11];
  const void* be2   = d_in[12];
  const void* Wih0  = d_in[13];
  const void* Whh0  = d_in[14];
  const void* bih0  = d_in[15];
  const void* bhh0  = d_in[16];
  const void* Wih1  = d_in[17];
  const void* Whh1  = d_in[18];
  const void* bih1  = d_in[19];
  const void* bhh1  = d_in[20];
  const void* W_out = d_in[21];
  const void* b_out = d_in[22];
  const int* src = eidx;
  const int* dst = eidx + EE;

  // workspace bump allocator (~114 MB)
  char* p = (char*)d_ws;
  auto alloc = [&](size_t bytes)->void*{ void* r = (void*)p; p += alignup(bytes); return r; };
  int*   flag     = (int*)  alloc(4);
  float* deg      = (float*)alloc(NN*4);
  float* dinv     = (float*)alloc(NN*4);
  float* selfn    = (float*)alloc(NN*4);
  int*   cnt      = (int*)  alloc(NN*4);
  int*   cursor   = (int*)  alloc(NN*4);
  int*   offs     = (int*)  alloc((NN+1)*4);
  int*   csr_src  = (int*)  alloc((size_t)EE*4);
  float* csr_norm = (float*)alloc((size_t)EE*4);
  float* W_inF = (float*)alloc(FF*HH*4);
  float* b_inF = (float*)alloc(HH*4);
  float* W1F   = (float*)alloc(HH*HH*4);
  float* g1F   = (float*)alloc(HH*4);
  float* be1F  = (float*)alloc(HH*4);
  float* W2F   = (float*)alloc(HH*HH*4);
  float* g2F   = (float*)alloc(HH*4);
  float* be2F  = (float*)alloc(HH*4);
  float* WihT0 = (float*)alloc(HH*3*HH*4);
  float* WhhT0 = (float*)alloc(HH*3*HH*4);
  float* bih0F = (float*)alloc(3*HH*4);
  float* bhh0F = (float*)alloc(3*HH*4);
  float* WihT1 = (float*)alloc(HH*3*HH*4);
  float* WhhT1 = (float*)alloc(HH*3*HH*4);
  float* bih1F = (float*)alloc(3*HH*4);
  float* bhh1F = (float*)alloc(3*HH*4);
  float* W_outF= (float*)alloc(HH*CC*4);
  float* b_outF= (float*)alloc(CC*4);
  float* sums  = (float*)alloc(2*HH*4);            // per-t BN: sum | sumsq
  float* xconv = (float*)alloc((size_t)NN*FF*4);   // 5.12 MB fp32 x_t staging
  float* temp1 = (float*)alloc((size_t)NN*HH*4);   // 10.24 MB
  float* temp2 = (float*)alloc((size_t)NN*HH*4);   // 10.24 MB
  float* h0buf = (float*)alloc((size_t)NN*HH*4);   // 10.24 MB
  float* h1buf = (float*)alloc((size_t)NN*HH*4);   // 10.24 MB
  float* gibuf = (float*)alloc((size_t)NN*3*HH*4); // 30.72 MB
  float* ghbuf = (float*)alloc((size_t)NN*3*HH*4); // 30.72 MB
  (void)ws_size; (void)n_in; (void)in_sizes; (void)out_size;

  const int TPB = 256;
  // ---- dtype probe ----
  k_detect<<<1, 256, 0, stream>>>(x_seq, flag);

  // ---- graph normalization + CSR ----
  k_init<<<ceil_div(NN,TPB), TPB, 0, stream>>>(deg, cnt, cursor, NN);
  k_deg <<<ceil_div(EE,TPB), TPB, 0, stream>>>(src, dst, ew, deg, cnt, EE, flag);
  k_dinv<<<ceil_div(NN,TPB), TPB, 0, stream>>>(deg, dinv, selfn, NN);
  k_scan<<<1, 256, 0, stream>>>(cnt, offs, NN);
  k_fill<<<ceil_div(EE,TPB), TPB, 0, stream>>>(src, dst, ew, dinv, offs, cursor, csr_src, csr_norm, EE, flag);

  // ---- weight conversion to fp32 (Wih/Whh transposed to [H,3H]) ----
  auto cvt = [&](const void* s, float* d, int n){ k_cvt<<<ceil_div(n,TPB), TPB, 0, stream>>>(s, 0, d, n, flag); };
  cvt(W_in, W_inF, FF*HH); cvt(b_in, b_inF, HH);
  cvt(W1, W1F, HH*HH); cvt(g1, g1F, HH); cvt(be1, be1F, HH);
  cvt(W2, W2F, HH*HH); cvt(g2, g2F, HH); cvt(be2, be2F, HH);
  cvt(bih0, bih0F, 3*HH); cvt(bhh0, bhh0F, 3*HH);
  cvt(bih1, bih1F, 3*HH); cvt(bhh1, bhh1F, 3*HH);
  cvt(W_out, W_outF, HH*CC); cvt(b_out, b_outF, CC);
  k_cvt_t<<<ceil_div(3*HH*HH,TPB), TPB, 0, stream>>>(Wih0, WihT0, 3*HH, HH, flag);
  k_cvt_t<<<ceil_div(3*HH*HH,TPB), TPB, 0, stream>>>(Whh0, WhhT0, 3*HH, HH, flag);
  k_cvt_t<<<ceil_div(3*HH*HH,TPB), TPB, 0, stream>>>(Wih1, WihT1, 3*HH, HH, flag);
  k_cvt_t<<<ceil_div(3*HH*HH,TPB), TPB, 0, stream>>>(Whh1, WhhT1, 3*HH, HH, flag);

  dim3 tb(16,16);
  dim3 g_nh (HH/64,   ceil_div(NN,64));   // [20000,*]@[*,128]
  dim3 g_gru(3*HH/64, ceil_div(NN,64));   // [20000,128]@[128,384]
  int totH = NN*HH;

  k_zero<<<ceil_div(totH,TPB), TPB, 0, stream>>>(h0buf, totH);
  k_zero<<<ceil_div(totH,TPB), TPB, 0, stream>>>(h1buf, totH);

  for (int t = 0; t < T_STEPS; t++){
    // stage x_t to fp32
    k_cvt<<<ceil_div(NN*FF,TPB), TPB, 0, stream>>>(x_seq, (long)t*NN*FF, xconv, NN*FF, flag);
    // GCN stack (per timestep, all fp32)
    k_gemm<1><<<g_nh, tb, 0, stream>>>(xconv, W_inF, b_inF, temp1, NN, HH, FF);
    k_gemm<0><<<g_nh, tb, 0, stream>>>(temp1, W1F, nullptr, temp2, NN, HH, HH);
    k_conv<<<NN, HH, 0, stream>>>(temp2, temp1, offs, csr_src, csr_norm, selfn);
    k_zero<<<1, 256, 0, stream>>>(sums, 2*HH);
    k_bnstats<<<40, 256, 0, stream>>>(temp1, sums);
    k_bnnorm<<<ceil_div(totH,TPB), TPB, 0, stream>>>(temp1, sums, g1F, be1F, totH);
    k_gemm<0><<<g_nh, tb, 0, stream>>>(temp1, W2F, nullptr, temp2, NN, HH, HH);
    k_conv<<<NN, HH, 0, stream>>>(temp2, temp1, offs, csr_src, csr_norm, selfn);
    k_zero<<<1, 256, 0, stream>>>(sums, 2*HH);
    k_bnstats<<<40, 256, 0, stream>>>(temp1, sums);
    k_bnnorm<<<ceil_div(totH,TPB), TPB, 0, stream>>>(temp1, sums, g2F, be2F, totH);
    // GRU layer 0 (in: temp1, state: h0buf)
    k_gemm<0><<<g_gru, tb, 0, stream>>>(temp1, WihT0, bih0F, gibuf, NN, 3*HH, HH);
    k_gemm<0><<<g_gru, tb, 0, stream>>>(h0buf, WhhT0, bhh0F, ghbuf, NN, 3*HH, HH);
    k_gru<<<ceil_div(totH,TPB), TPB, 0, stream>>>(gibuf, ghbuf, h0buf, totH);
    // GRU layer 1 (in: h0buf, state: h1buf)
    k_gemm<0><<<g_gru, tb, 0, stream>>>(h0buf, WihT1, bih1F, gibuf, NN, 3*HH, HH);
    k_gemm<0><<<g_gru, tb, 0, stream>>>(h1buf, WhhT1, bhh1F, ghbuf, NN, 3*HH, HH);
    k_gru<<<ceil_div(totH,TPB), TPB, 0, stream>>>(gibuf, ghbuf, h1buf, totH);
  }

  // ---- output head ----
  k_out<<<ceil_div(NN,16), 256, 0, stream>>>(h1buf, W_outF, b_outF, d_out, NN, flag);
}